// Round 10
// baseline (492.054 us; speedup 1.0000x reference)
//
#include <hip/hip_runtime.h>

// Problem dims
#define B_DIM 64
#define IN_CH 16
#define H_DIM 256
#define FDIM  128
#define NF    1001
#define INS0  144      // FDIM + IN_CH
#define TB    7        // timesteps per block in prep gf-role (1001 = 7*143)
#define U     7        // timesteps per pipeline epoch (1001 = 7*143, exact)
#define NEPOCH 143
#define GF_BLOCKS 143

// Gate pre-activations are PRE-SCALED so they feed v_exp_f32 (exp2) directly:
//   rows i,f,o:  scale = -log2(e)    -> exp2(arg) = e^{-gate}
//   row  g:      scale = -2*log2(e)  -> exp2(arg) = e^{-2*gate}
#define SC_IFO (-1.44269504088896340736f)
#define SC_G   (-2.88539008177792681472f)

__device__ __forceinline__ float gate_scale(int j) {
    return (j >= 512 && j < 768) ? SC_G : SC_IFO;
}

// ---------------------------------------------------------------------------
// Wave64 sum-reduce via DPP (VALU-rate). Result broadcast via readlane 63.
// ---------------------------------------------------------------------------
template<int CTRL, int ROW_MASK>
__device__ __forceinline__ float dpp_add(float x) {
    int y = __builtin_amdgcn_update_dpp(0, __float_as_int(x), CTRL, ROW_MASK, 0xf, true);
    return x + __int_as_float(y);
}
__device__ __forceinline__ float wave_allreduce(float x) {
    x = dpp_add<0x111, 0xf>(x);   // row_shr:1
    x = dpp_add<0x112, 0xf>(x);   // row_shr:2
    x = dpp_add<0x114, 0xf>(x);   // row_shr:4
    x = dpp_add<0x118, 0xf>(x);   // row_shr:8
    x = dpp_add<0x142, 0xa>(x);   // row_bcast:15 into rows 1,3
    x = dpp_add<0x143, 0xc>(x);   // row_bcast:31 into rows 2,3
    return __int_as_float(__builtin_amdgcn_readlane(__float_as_int(x), 63));
}

// ---------------------------------------------------------------------------
// Merged prep kernel. Blocks [0,143): Gf[t][j] = (f[t]·Wih0[j][:128])*scale(j).
// Blocks [143,207): Gxb[b][j] = (x[b]·Wih0[j][128:] + bih0[j]+bhh0[j])*scale(j).
// ---------------------------------------------------------------------------
__global__ __launch_bounds__(1024) void prep_kernel(
    const float* __restrict__ f, const float* __restrict__ x,
    const float* __restrict__ W,
    const float* __restrict__ bih, const float* __restrict__ bhh,
    float* __restrict__ Gf, float* __restrict__ Gxb)
{
    const int tid = threadIdx.x;
    const int j = tid;
    if (blockIdx.x < GF_BLOCKS) {
        __shared__ float fs[TB][FDIM];
        const int t0 = blockIdx.x * TB;
        for (int i = tid; i < TB * FDIM; i += 1024)
            fs[i >> 7][i & 127] = f[t0 * FDIM + i];
        __syncthreads();

        const float4* w4 = (const float4*)(W + j * INS0);
        float acc[TB];
#pragma unroll
        for (int t = 0; t < TB; ++t) acc[t] = 0.f;
#pragma unroll
        for (int kc = 0; kc < 8; ++kc) {
            float4 a = w4[kc * 4 + 0];
            float4 b = w4[kc * 4 + 1];
            float4 c = w4[kc * 4 + 2];
            float4 d = w4[kc * 4 + 3];
#pragma unroll
            for (int t = 0; t < TB; ++t) {
                const float* fp = &fs[t][kc * 16];
                float s = acc[t];
                s = fmaf(a.x, fp[0], s);  s = fmaf(a.y, fp[1], s);
                s = fmaf(a.z, fp[2], s);  s = fmaf(a.w, fp[3], s);
                s = fmaf(b.x, fp[4], s);  s = fmaf(b.y, fp[5], s);
                s = fmaf(b.z, fp[6], s);  s = fmaf(b.w, fp[7], s);
                s = fmaf(c.x, fp[8], s);  s = fmaf(c.y, fp[9], s);
                s = fmaf(c.z, fp[10], s); s = fmaf(c.w, fp[11], s);
                s = fmaf(d.x, fp[12], s); s = fmaf(d.y, fp[13], s);
                s = fmaf(d.z, fp[14], s); s = fmaf(d.w, fp[15], s);
                acc[t] = s;
            }
        }
        const float sc = gate_scale(j);
#pragma unroll
        for (int t = 0; t < TB; ++t)
            Gf[(size_t)(t0 + t) * 1024 + j] = acc[t] * sc;
    } else {
        const int b = blockIdx.x - GF_BLOCKS;
        const float* w = W + j * INS0 + FDIM;
        const float* xb = x + b * IN_CH;
        float s = bih[j] + bhh[j];
#pragma unroll
        for (int k = 0; k < IN_CH; ++k) s = fmaf(xb[k], w[k], s);
        Gxb[b * 1024 + j] = s * gate_scale(j);
    }
}

// ---------------------------------------------------------------------------
// Main recurrence, epoch-pipelined (391us structure) + pairwise-shared rcps:
// per lane-step 20 exp + 4 rcp (was +8 rcp). For independent units j,k:
//   r = rcp(P_j*P_k); inv_j = r*P_k; inv_k = r*P_j   (exact reformulation)
// Per-unit math: A=e^-gi B=e^-2gg D=e^-gf F=e^-go C=e^-2c
//   inv1 = 1/((1+A)(1+B)(1+D)):  si*tg=(1-B)(1+D)inv1 ; sf=(1+A)(1+B)inv1
//   inv2 = 1/((1+F)(1+C)):       hr=(1-C)inv2
// Issue model: 24 trans x ~25cy + ~120 VALU x 2cy ~= 845 cy/step.
// ---------------------------------------------------------------------------
__global__ __launch_bounds__(192) void lstm_pipeline(
    const float* __restrict__ Gf, const float* __restrict__ Gxb,
    const float* __restrict__ Whh0, const float* __restrict__ Whr0,
    const float* __restrict__ Wih1, const float* __restrict__ Whh1,
    const float* __restrict__ bih1, const float* __restrict__ bhh1,
    const float* __restrict__ Whr1,
    const float* __restrict__ Wih2, const float* __restrict__ Whh2,
    const float* __restrict__ bih2, const float* __restrict__ bhh2,
    const float* __restrict__ Whr2,
    float* __restrict__ out)
{
    const int b    = blockIdx.x;
    const int wave = threadIdx.x >> 6;
    const int lane = threadIdx.x & 63;
    const int jb   = lane * 4;

    __shared__ float hbuf[3][2][U];   // [layer][parity][step-in-epoch]

    float base[16];   // wave0: Gxb (pre-scaled); wave1/2: (bih+bhh)*scale
    float wih[16];    // wave1/2: W_ih column * scale
    float whh[16];    // recurrent column * scale
    float whr[4];     // projection row slice (unscaled)

    const float *whh_p, *whr_p;
    if (wave == 0)      { whh_p = Whh0; whr_p = Whr0; }
    else if (wave == 1) { whh_p = Whh1; whr_p = Whr1; }
    else                { whh_p = Whh2; whr_p = Whr2; }

#pragma unroll
    for (int g = 0; g < 4; ++g) {
        const float sc = (g == 2) ? SC_G : SC_IFO;
        float4 w = *(const float4*)(whh_p + g * 256 + jb);
        whh[g*4+0] = w.x * sc; whh[g*4+1] = w.y * sc;
        whh[g*4+2] = w.z * sc; whh[g*4+3] = w.w * sc;
    }
    {
        float4 w = *(const float4*)(whr_p + jb);
        whr[0] = w.x; whr[1] = w.y; whr[2] = w.z; whr[3] = w.w;
    }

    if (wave == 0) {
#pragma unroll
        for (int g = 0; g < 4; ++g) {
            float4 v = *(const float4*)(Gxb + b * 1024 + g * 256 + jb);
            base[g*4+0] = v.x; base[g*4+1] = v.y; base[g*4+2] = v.z; base[g*4+3] = v.w;
            wih[g*4+0] = 0.f; wih[g*4+1] = 0.f; wih[g*4+2] = 0.f; wih[g*4+3] = 0.f;
        }
    } else {
        const float* bi = (wave == 1) ? bih1 : bih2;
        const float* bh = (wave == 1) ? bhh1 : bhh2;
        const float* wi = (wave == 1) ? Wih1 : Wih2;
#pragma unroll
        for (int g = 0; g < 4; ++g) {
            const float sc = (g == 2) ? SC_G : SC_IFO;
            float4 v1 = *(const float4*)(bi + g * 256 + jb);
            float4 v2 = *(const float4*)(bh + g * 256 + jb);
            float4 v3 = *(const float4*)(wi + g * 256 + jb);
            base[g*4+0] = (v1.x + v2.x) * sc; base[g*4+1] = (v1.y + v2.y) * sc;
            base[g*4+2] = (v1.z + v2.z) * sc; base[g*4+3] = (v1.w + v2.w) * sc;
            wih[g*4+0] = v3.x * sc; wih[g*4+1] = v3.y * sc;
            wih[g*4+2] = v3.z * sc; wih[g*4+3] = v3.w * sc;
        }
    }

    float c4[4] = {0.f, 0.f, 0.f, 0.f};
    float h_state = 0.f;

    for (int e = 0; e < NEPOCH + 2; ++e) {
        __syncthreads();
        const int te = e - wave;                  // this wave's epoch index
        const bool active = (te >= 0) && (te < NEPOCH);

        float pre[U][16];   // h-independent pre-scaled gate contribution

        if (active) {
            if (wave == 0) {
                const float* p = Gf + (size_t)te * U * 1024;
#pragma unroll
                for (int u = 0; u < U; ++u) {
#pragma unroll
                    for (int g = 0; g < 4; ++g) {
                        float4 v = *(const float4*)(p + u * 1024 + g * 256 + jb);
                        pre[u][g*4+0] = v.x + base[g*4+0];
                        pre[u][g*4+1] = v.y + base[g*4+1];
                        pre[u][g*4+2] = v.z + base[g*4+2];
                        pre[u][g*4+3] = v.w + base[g*4+3];
                    }
                }
            } else {
                const int par = (e - 1) & 1;
#pragma unroll
                for (int u = 0; u < U; ++u) {
                    float hin = hbuf[wave - 1][par][u];
#pragma unroll
                    for (int i = 0; i < 16; ++i)
                        pre[u][i] = fmaf(hin, wih[i], base[i]);
                }
            }

#pragma unroll
            for (int u = 0; u < U; ++u) {
                // Phase 1: gate exps and P = (1+A)(1+B)(1+D) for all 4 units
                float Bv[4], Dv1[4], p1a[4], Pa[4], f1a[4];
#pragma unroll
                for (int jj = 0; jj < 4; ++jj) {
                    float gi_s = fmaf(h_state, whh[0*4+jj], pre[u][0*4+jj]);
                    float gf_s = fmaf(h_state, whh[1*4+jj], pre[u][1*4+jj]);
                    float gg_s = fmaf(h_state, whh[2*4+jj], pre[u][2*4+jj]);
                    float go_s = fmaf(h_state, whh[3*4+jj], pre[u][3*4+jj]);
                    float A  = __builtin_amdgcn_exp2f(gi_s);   // e^-gi
                    float Dv = __builtin_amdgcn_exp2f(gf_s);   // e^-gf
                    float B_ = __builtin_amdgcn_exp2f(gg_s);   // e^-2gg
                    float Fv = __builtin_amdgcn_exp2f(go_s);   // e^-go
                    float a1 = 1.f + A, b1 = 1.f + B_, d1 = 1.f + Dv;
                    Bv[jj] = B_; f1a[jj] = 1.f + Fv;
                    Dv1[jj] = d1;
                    p1a[jj] = a1 * b1;
                    Pa[jj]  = p1a[jj] * d1;
                }
                // Pairwise-shared rcp for inv1 = 1/P
                float r01 = __builtin_amdgcn_rcpf(Pa[0] * Pa[1]);
                float r23 = __builtin_amdgcn_rcpf(Pa[2] * Pa[3]);
                float inv1[4];
                inv1[0] = r01 * Pa[1]; inv1[1] = r01 * Pa[0];
                inv1[2] = r23 * Pa[3]; inv1[3] = r23 * Pa[2];

                // Phase 2: c-update, C exps, Q = (1+F)(1+C)
                float Cv[4], Qa[4];
#pragma unroll
                for (int jj = 0; jj < 4; ++jj) {
                    float si_tg = (1.f - Bv[jj]) * Dv1[jj] * inv1[jj];
                    float sf    = p1a[jj] * inv1[jj];
                    float c = fmaf(sf, c4[jj], si_tg);
                    c4[jj] = c;
                    Cv[jj] = __builtin_amdgcn_exp2f(SC_G * c);  // e^-2c
                    Qa[jj] = f1a[jj] * (1.f + Cv[jj]);
                }
                // Pairwise-shared rcp for inv2 = 1/Q
                float q01 = __builtin_amdgcn_rcpf(Qa[0] * Qa[1]);
                float q23 = __builtin_amdgcn_rcpf(Qa[2] * Qa[3]);
                float m0 = (1.f - Cv[0]) * (q01 * Qa[1]) * whr[0];
                float m1 = (1.f - Cv[1]) * (q01 * Qa[0]) * whr[1];
                float m2 = (1.f - Cv[2]) * (q23 * Qa[3]) * whr[2];
                float m3 = (1.f - Cv[3]) * (q23 * Qa[2]) * whr[3];

                float contrib = (m0 + m1) + (m2 + m3);
                float tot = wave_allreduce(contrib);
                h_state = tot;
                if (lane == 0) hbuf[wave][e & 1][u] = tot;
                if (wave == 2 && lane == 0)
                    out[(size_t)b * NF + te * U + u] = tot;
            }
        }
    }
}

// ---------------------------------------------------------------------------
extern "C" void kernel_launch(void* const* d_in, const int* in_sizes, int n_in,
                              void* d_out, int out_size, void* d_ws, size_t ws_size,
                              hipStream_t stream)
{
    const float* x    = (const float*)d_in[0];
    const float* f    = (const float*)d_in[1];
    const float* Wih0 = (const float*)d_in[2];
    const float* Whh0 = (const float*)d_in[3];
    const float* bih0 = (const float*)d_in[4];
    const float* bhh0 = (const float*)d_in[5];
    const float* Whr0 = (const float*)d_in[6];
    const float* Wih1 = (const float*)d_in[7];
    const float* Whh1 = (const float*)d_in[8];
    const float* bih1 = (const float*)d_in[9];
    const float* bhh1 = (const float*)d_in[10];
    const float* Whr1 = (const float*)d_in[11];
    const float* Wih2 = (const float*)d_in[12];
    const float* Whh2 = (const float*)d_in[13];
    const float* bih2 = (const float*)d_in[14];
    const float* bhh2 = (const float*)d_in[15];
    const float* Whr2 = (const float*)d_in[16];
    float* out = (float*)d_out;

    float* Gf  = (float*)d_ws;                       // NF * 1024 floats (4.1 MB)
    float* Gxb = Gf + (size_t)NF * 1024;             // 64 * 1024 floats

    prep_kernel<<<GF_BLOCKS + B_DIM, 1024, 0, stream>>>(f, x, Wih0, bih0, bhh0,
                                                        Gf, Gxb);
    lstm_pipeline<<<B_DIM, 192, 0, stream>>>(Gf, Gxb, Whh0, Whr0,
                                             Wih1, Whh1, bih1, bhh1, Whr1,
                                             Wih2, Whh2, bih2, bhh2, Whr2,
                                             out);
}